// Round 5
// baseline (450.249 us; speedup 1.0000x reference)
//
#include <hip/hip_runtime.h>
#include <math.h>

#define BB 1024
#define NN 1024
#define DD 64
#define MARGIN_V 0.5f
#define EPS_V 1e-6f
#define QSPLIT 4               // blocks per batch row in k_dist
#define QCOLS (NN / QSPLIT)    // 256 columns per block

typedef float f32x4 __attribute__((ext_vector_type(4)));

// ---------------------------------------------------------------------------
// Kernel 1: 4096 blocks = 4 per batch row. THREAD-PER-COLUMN: thread t owns
// column n = q*256 + t. It reads its own 64 floats from each of a/p/g
// (4 cachelines x 4 f32x4 loads each; each 64B line is fully consumed by 4
// consecutive loads -> 75% L1 hit) and accumulates dp/dn in 8 independent
// chains. NO cross-lane ops in the loop -> 48 independent loads visible to
// the scheduler (fixes the latency wall: round-4 showed shfl-per-iter
// structure pinned delivered BW at 4 TB/s with VGPR=36).
// Wave argmax/loss reduce happens once at the end.
// ---------------------------------------------------------------------------
__global__ __launch_bounds__(256) void k_dist(const float* __restrict__ a,
                                              const float* __restrict__ p,
                                              const float* __restrict__ g,
                                              float* __restrict__ ws_loss,
                                              float* __restrict__ ws_score,
                                              int* __restrict__ ws_idx,
                                              int* __restrict__ ws_valid)
{
    const int blk = blockIdx.x;        // 0..4095
    const int b   = blk >> 2;
    const int q   = blk & 3;
    const int tid = threadIdx.x;       // 0..255
    const int n   = q * QCOLS + tid;   // column owned by this thread

    const float* pa = a + (size_t)b * (NN * DD) + (size_t)n * DD;
    const float* pp = p + (size_t)b * (NN * DD) + (size_t)n * DD;
    const float* pg = g + (size_t)b * (NN * DD) + (size_t)n * DD;

    float dp0 = 0.f, dp1 = 0.f, dn0 = 0.f, dn1 = 0.f;

    #pragma unroll
    for (int c = 0; c < 4; ++c) {      // cacheline c = floats [c*16, c*16+16)
        f32x4 va[4], vp[4], vg[4];
        #pragma unroll
        for (int s = 0; s < 4; ++s)
            va[s] = __builtin_nontemporal_load((const f32x4*)(pa + c * 16 + s * 4));
        #pragma unroll
        for (int s = 0; s < 4; ++s)
            vp[s] = __builtin_nontemporal_load((const f32x4*)(pp + c * 16 + s * 4));
        #pragma unroll
        for (int s = 0; s < 4; ++s)
            vg[s] = *(const f32x4*)(pg + c * 16 + s * 4);

        float accp0 = 0.f, accp1 = 0.f, accn0 = 0.f, accn1 = 0.f, t;
        #pragma unroll
        for (int s = 0; s < 4; s += 2) {
            #pragma unroll
            for (int e = 0; e < 4; ++e) {
                t = va[s][e]     - vp[s][e]     + EPS_V; accp0 += t * t;
                t = va[s][e]     - vg[s][e]     + EPS_V; accn0 += t * t;
                t = va[s + 1][e] - vp[s + 1][e] + EPS_V; accp1 += t * t;
                t = va[s + 1][e] - vg[s + 1][e] + EPS_V; accn1 += t * t;
            }
        }
        dp0 += accp0; dp1 += accp1;
        dn0 += accn0; dn1 += accn1;
    }

    const float dpt = dp0 + dp1;
    const float dnt = dn0 + dn1;

    // per-column tail (all 256 lanes active, one column each)
    const float dist_pos = sqrtf(dpt);
    const float dist_neg = sqrtf(dnt);
    const float diff = MARGIN_V + dist_pos - dist_neg;
    float loss  = fmaxf(diff, 0.f);
    float score = (diff > 0.f) ? dist_neg : -INFINITY;
    int   idx   = n;

    // wave reduce: sum(loss), argmax(score) with first-index tie-break
    for (int m = 1; m < 64; m <<= 1) {
        loss += __shfl_xor(loss, m, 64);
        const float so = __shfl_xor(score, m, 64);
        const int   io = __shfl_xor(idx, m, 64);
        if (so > score || (so == score && io < idx)) { score = so; idx = io; }
    }

    __shared__ float s_loss[4];
    __shared__ float s_score[4];
    __shared__ int   s_idx[4];
    const int wave = tid >> 6;
    if ((tid & 63) == 0) {
        s_loss[wave]  = loss;
        s_score[wave] = score;
        s_idx[wave]   = idx;
    }
    __syncthreads();
    if (tid == 0) {
        float ls = 0.f, bs = -INFINITY;
        int   bi = 0x7fffffff;
        for (int k = 0; k < 4; ++k) {
            ls += s_loss[k];
            const float sc = s_score[k]; const int ix = s_idx[k];
            if (sc > bs || (sc == bs && ix < bi)) { bs = sc; bi = ix; }
        }
        ws_loss[blk]  = ls;
        ws_score[blk] = bs;
        ws_idx[blk]   = bi;
        ws_valid[blk] = (bs > -INFINITY) ? 1 : 0;
    }
}

// ---------------------------------------------------------------------------
// Kernel 2 (single block, 1024 threads): thread b merges its QSPLIT partials
// (first-index tie-break), writes sel/has_valid, block-reduces loss -> mean.
// ---------------------------------------------------------------------------
__global__ __launch_bounds__(1024) void k_merge(const float* __restrict__ ws_loss,
                                                const float* __restrict__ ws_score,
                                                const int* __restrict__ ws_idx,
                                                const int* __restrict__ ws_valid,
                                                float* __restrict__ out_loss,
                                                int* __restrict__ ws_sel,
                                                float* __restrict__ out_hasvalid)
{
    const int b = threadIdx.x;
    float ls = 0.f;
    float bs = -INFINITY;
    int   bi = 0x7fffffff;
    int   av = 0;
    for (int qq = 0; qq < QSPLIT; ++qq) {
        const int idx = b * QSPLIT + qq;
        const float sc = ws_score[idx];
        const int   ix = ws_idx[idx];
        if (sc > bs || (sc == bs && ix < bi)) { bs = sc; bi = ix; }
        ls += ws_loss[idx];
        av |= ws_valid[idx];
    }
    ws_sel[b] = bi;
    out_hasvalid[b] = av ? 1.0f : 0.0f;

    __shared__ float s[16];
    float v = ls;
    for (int m = 1; m < 64; m <<= 1) v += __shfl_xor(v, m, 64);
    if ((b & 63) == 0) s[b >> 6] = v;
    __syncthreads();
    if (b == 0) {
        float tot = 0.f;
        for (int k = 0; k < 16; ++k) tot += s[k];
        out_loss[0] = tot / (float)((size_t)BB * NN);
    }
}

// ---------------------------------------------------------------------------
// Kernel 3: hard_neg[b] = negative[sel_col[b]].  Scalar coalesced copies
// (dst is 4B-misaligned vs 16B). Non-temporal stores: output never re-read.
// ---------------------------------------------------------------------------
__global__ __launch_bounds__(256) void k_gather(const float* __restrict__ g,
                                                const int* __restrict__ ws_sel,
                                                float* __restrict__ out_hn)
{
    const int b   = blockIdx.y;
    const int sel = ws_sel[b];
    const float* __restrict__ src = g      + (size_t)sel * (NN * DD);
    float* __restrict__       dst = out_hn + (size_t)b   * (NN * DD);
    const int t = blockIdx.x * blockDim.x + threadIdx.x;   // 0..8191
    #pragma unroll
    for (int k = 0; k < (NN * DD) / 8192; ++k) {
        const int idx = t + k * 8192;
        __builtin_nontemporal_store(src[idx], dst + idx);
    }
}

extern "C" void kernel_launch(void* const* d_in, const int* in_sizes, int n_in,
                              void* d_out, int out_size, void* d_ws, size_t ws_size,
                              hipStream_t stream) {
    const float* anchor   = (const float*)d_in[0];
    const float* positive = (const float*)d_in[1];
    const float* negative = (const float*)d_in[2];
    float* out = (float*)d_out;

    // out layout: [0] loss | [1 .. 1+B*N*D) hard_neg | [1+B*N*D .. +B) has_valid
    float* out_loss     = out;
    float* out_hard_neg = out + 1;
    float* out_hasvalid = out + 1 + (size_t)BB * NN * DD;

    // ws layout: 4096 loss | 4096 score | 4096 idx | 4096 valid | 1024 sel
    float* ws_loss  = (float*)d_ws;
    float* ws_score = ws_loss + BB * QSPLIT;
    int*   ws_idx   = (int*)(ws_score + BB * QSPLIT);
    int*   ws_valid = ws_idx + BB * QSPLIT;
    int*   ws_sel   = ws_valid + BB * QSPLIT;

    k_dist<<<dim3(BB * QSPLIT), dim3(256), 0, stream>>>(anchor, positive, negative,
                                                        ws_loss, ws_score, ws_idx, ws_valid);
    k_merge<<<dim3(1), dim3(1024), 0, stream>>>(ws_loss, ws_score, ws_idx, ws_valid,
                                                out_loss, ws_sel, out_hasvalid);
    k_gather<<<dim3(32, BB), dim3(256), 0, stream>>>(negative, ws_sel, out_hard_neg);
}

// Round 6
// 213.252 us; speedup vs baseline: 2.1114x; 2.1114x over previous
//
#include <hip/hip_runtime.h>
#include <math.h>

#define BB 1024
#define NN 1024
#define DD 64
#define MARGIN_V 0.5f
#define EPS_V 1e-6f
#define QSPLIT 4               // blocks per batch row in k_dist
#define QCOLS (NN / QSPLIT)    // 256 columns per block

typedef float f32x4 __attribute__((ext_vector_type(4)));

// ---------------------------------------------------------------------------
// Kernel 1: 4096 blocks = 4 per batch row. Coalesced group-of-16 layout
// (round-4 addressing: lane gl reads f32x4 at column n, elem gl*4; a wave's
// 4 groups cover 4 consecutive columns -> 1KB/instr contiguous).
// Key change vs round 4: NO cross-lane ops inside the load bursts. Each half
// issues 24 independent loads (8 cols x 3 arrays) and accumulates per-lane
// partials into statically-indexed arrays; the 16-lane-group shfl reduces
// run AFTER the burst. 4x more loads per stall region -> higher MLP.
// ---------------------------------------------------------------------------
__global__ __launch_bounds__(256) void k_dist(const float* __restrict__ a,
                                              const float* __restrict__ p,
                                              const float* __restrict__ g,
                                              float* __restrict__ ws_loss,
                                              float* __restrict__ ws_score,
                                              int* __restrict__ ws_idx,
                                              int* __restrict__ ws_valid)
{
    const int blk  = blockIdx.x;       // 0..4095
    const int b    = blk >> 2;
    const int q    = blk & 3;
    const int tid  = threadIdx.x;
    const int lane = tid & 63;
    const int wave = tid >> 6;         // 0..3
    const int grp  = lane >> 4;        // 0..3
    const int gl   = lane & 15;        // lane within 16-lane group
    const int group = wave * 4 + grp;  // 0..15

    const size_t base  = (size_t)b * (NN * DD);
    const int    ncol0 = q * QCOLS + group;   // group's cols: ncol0 + i*16, i=0..15

    float loss_acc   = 0.f;
    float best_score = -INFINITY;
    int   best_idx   = 0x7fffffff;

    #pragma unroll 1
    for (int h = 0; h < 2; ++h) {
        // ---- load burst: 24 independent coalesced loads, zero cross-lane ----
        f32x4 va[8], vp[8], vg[8];
        #pragma unroll
        for (int i = 0; i < 8; ++i) {
            const int n = ncol0 + (h * 8 + i) * 16;
            const size_t off = base + (size_t)n * DD + (size_t)gl * 4;
            va[i] = __builtin_nontemporal_load((const f32x4*)(a + off));
            vp[i] = __builtin_nontemporal_load((const f32x4*)(p + off));
            vg[i] = *(const f32x4*)(g + off);
        }

        // ---- pure-VALU accumulate (per-lane partials, static indices) ----
        float accp[8], accn[8];
        #pragma unroll
        for (int i = 0; i < 8; ++i) {
            float sp = 0.f, sn = 0.f, t;
            #pragma unroll
            for (int e = 0; e < 4; ++e) {
                t = va[i][e] - vp[i][e] + EPS_V; sp += t * t;
                t = va[i][e] - vg[i][e] + EPS_V; sn += t * t;
            }
            accp[i] = sp; accn[i] = sn;
        }

        // ---- batched 16-lane-group reduces (32 independent 4-deep chains) ----
        #pragma unroll
        for (int i = 0; i < 8; ++i) {
            #pragma unroll
            for (int m = 1; m < 16; m <<= 1) {
                accp[i] += __shfl_xor(accp[i], m, 64);
                accn[i] += __shfl_xor(accn[i], m, 64);
            }
        }

        // ---- tail: lane gl==i owns column (h*8+i) ----
        #pragma unroll
        for (int i = 0; i < 8; ++i) {
            if (gl == i) {
                const int n = ncol0 + (h * 8 + i) * 16;
                const float diff = MARGIN_V + sqrtf(accp[i]) - sqrtf(accn[i]);
                loss_acc += fmaxf(diff, 0.f);
                const float sc = (diff > 0.f) ? sqrtf(accn[i]) : -INFINITY;
                if (sc > best_score || (sc == best_score && n < best_idx)) {
                    best_score = sc; best_idx = n;
                }
            }
        }
    }

    // ---- wave reduce: sum(loss), argmax(score) with first-index tie-break ----
    for (int m = 1; m < 64; m <<= 1) {
        loss_acc += __shfl_xor(loss_acc, m, 64);
        const float so = __shfl_xor(best_score, m, 64);
        const int   io = __shfl_xor(best_idx, m, 64);
        if (so > best_score || (so == best_score && io < best_idx)) {
            best_score = so; best_idx = io;
        }
    }

    __shared__ float s_loss[4];
    __shared__ float s_score[4];
    __shared__ int   s_idx[4];
    if ((tid & 63) == 0) {
        s_loss[wave]  = loss_acc;
        s_score[wave] = best_score;
        s_idx[wave]   = best_idx;
    }
    __syncthreads();
    if (tid == 0) {
        float ls = 0.f, bs = -INFINITY;
        int   bi = 0x7fffffff;
        for (int k = 0; k < 4; ++k) {
            ls += s_loss[k];
            const float sc = s_score[k]; const int ix = s_idx[k];
            if (sc > bs || (sc == bs && ix < bi)) { bs = sc; bi = ix; }
        }
        ws_loss[blk]  = ls;
        ws_score[blk] = bs;
        ws_idx[blk]   = bi;
        ws_valid[blk] = (bs > -INFINITY) ? 1 : 0;
    }
}

// ---------------------------------------------------------------------------
// Kernel 2 (single block, 1024 threads): thread b merges its QSPLIT partials
// (first-index tie-break), writes sel/has_valid, block-reduces loss -> mean.
// ---------------------------------------------------------------------------
__global__ __launch_bounds__(1024) void k_merge(const float* __restrict__ ws_loss,
                                                const float* __restrict__ ws_score,
                                                const int* __restrict__ ws_idx,
                                                const int* __restrict__ ws_valid,
                                                float* __restrict__ out_loss,
                                                int* __restrict__ ws_sel,
                                                float* __restrict__ out_hasvalid)
{
    const int b = threadIdx.x;
    float ls = 0.f;
    float bs = -INFINITY;
    int   bi = 0x7fffffff;
    int   av = 0;
    for (int qq = 0; qq < QSPLIT; ++qq) {
        const int idx = b * QSPLIT + qq;
        const float sc = ws_score[idx];
        const int   ix = ws_idx[idx];
        if (sc > bs || (sc == bs && ix < bi)) { bs = sc; bi = ix; }
        ls += ws_loss[idx];
        av |= ws_valid[idx];
    }
    ws_sel[b] = bi;
    out_hasvalid[b] = av ? 1.0f : 0.0f;

    __shared__ float s[16];
    float v = ls;
    for (int m = 1; m < 64; m <<= 1) v += __shfl_xor(v, m, 64);
    if ((b & 63) == 0) s[b >> 6] = v;
    __syncthreads();
    if (b == 0) {
        float tot = 0.f;
        for (int k = 0; k < 16; ++k) tot += s[k];
        out_loss[0] = tot / (float)((size_t)BB * NN);
    }
}

// ---------------------------------------------------------------------------
// Kernel 3: hard_neg[b] = negative[sel_col[b]].  Scalar coalesced copies
// (dst is 4B-misaligned vs 16B). Non-temporal stores: output never re-read.
// ---------------------------------------------------------------------------
__global__ __launch_bounds__(256) void k_gather(const float* __restrict__ g,
                                                const int* __restrict__ ws_sel,
                                                float* __restrict__ out_hn)
{
    const int b   = blockIdx.y;
    const int sel = ws_sel[b];
    const float* __restrict__ src = g      + (size_t)sel * (NN * DD);
    float* __restrict__       dst = out_hn + (size_t)b   * (NN * DD);
    const int t = blockIdx.x * blockDim.x + threadIdx.x;   // 0..8191
    #pragma unroll
    for (int k = 0; k < (NN * DD) / 8192; ++k) {
        const int idx = t + k * 8192;
        __builtin_nontemporal_store(src[idx], dst + idx);
    }
}

extern "C" void kernel_launch(void* const* d_in, const int* in_sizes, int n_in,
                              void* d_out, int out_size, void* d_ws, size_t ws_size,
                              hipStream_t stream) {
    const float* anchor   = (const float*)d_in[0];
    const float* positive = (const float*)d_in[1];
    const float* negative = (const float*)d_in[2];
    float* out = (float*)d_out;

    // out layout: [0] loss | [1 .. 1+B*N*D) hard_neg | [1+B*N*D .. +B) has_valid
    float* out_loss     = out;
    float* out_hard_neg = out + 1;
    float* out_hasvalid = out + 1 + (size_t)BB * NN * DD;

    // ws layout: 4096 loss | 4096 score | 4096 idx | 4096 valid | 1024 sel
    float* ws_loss  = (float*)d_ws;
    float* ws_score = ws_loss + BB * QSPLIT;
    int*   ws_idx   = (int*)(ws_score + BB * QSPLIT);
    int*   ws_valid = ws_idx + BB * QSPLIT;
    int*   ws_sel   = ws_valid + BB * QSPLIT;

    k_dist<<<dim3(BB * QSPLIT), dim3(256), 0, stream>>>(anchor, positive, negative,
                                                        ws_loss, ws_score, ws_idx, ws_valid);
    k_merge<<<dim3(1), dim3(1024), 0, stream>>>(ws_loss, ws_score, ws_idx, ws_valid,
                                                out_loss, ws_sel, out_hasvalid);
    k_gather<<<dim3(32, BB), dim3(256), 0, stream>>>(negative, ws_sel, out_hard_neg);
}